// Round 12
// baseline (119.433 us; speedup 1.0000x reference)
//
#include <hip/hip_runtime.h>
#include <math.h>

namespace {

constexpr int Hh = 384;
constexpr int Ww = 384;
constexpr int Bb = 4;
constexpr int HW = Hh * Ww;          // 147456
constexpr int NPIX = Bb * HW;        // 589824
constexpr int TPB = 256;

constexpr int TILE_W = 64;
constexpr int TILE_H = 8;
constexpr int TX = Ww / TILE_W;              // 6
constexpr int TY = Hh / TILE_H;              // 48
constexpr int BLKS_PER_B = TX * TY;          // 288
constexpr int NBLK = Bb * BLKS_PER_B;        // 1152

// width-4 halo staged per launch: rows row0-4..row0+11 (16), col bytes col0-4..col0+67 (72)
constexpr int SR = 16;
constexpr int SCB = 72;
constexpr int SDW = SCB / 4;                 // 18 dwords/row
constexpr int STOT = SR * SDW;               // 288 dwords

// shell region: local coords lr 1..14, lc 1..70
constexpr int REG_W = 70;
constexpr int REGN = 14 * REG_W;             // 980 pixels

__device__ __forceinline__ float fsub_rn_(float a, float b) {
    return __fadd_rn(a, -b);
}

// 9 pairwise weights for pixel (h,w); /0.5 folded to *2.0 (exact, bit-identical)
__device__ __forceinline__ void compute_weights(const float* __restrict__ fmb,
                                                int h, int w, int hw,
                                                float* __restrict__ wgt) {
    float c0 = __fadd_rn(fmb[0 * HW + hw], 10.0f);
    float c1 = __fadd_rn(fmb[1 * HW + hw], 10.0f);
    float c2 = __fadd_rn(fmb[2 * HW + hw], 10.0f);
#pragma unroll
    for (int ki = 0; ki < 3; ++ki) {
#pragma unroll
        for (int kj = 0; kj < 3; ++kj) {
            const int k = ki * 3 + kj;
            const int hh = h + ki - 1;
            const int ww2 = w + kj - 1;
            if (hh < 0 || hh >= Hh || ww2 < 0 || ww2 >= Ww) {
                wgt[k] = 0.0f;   // OOB taps contribute exact +0.0
            } else {
                const int nhw = hh * Ww + ww2;
                float d0 = fsub_rn_(__fadd_rn(fmb[0 * HW + nhw], 10.0f), c0);
                float d1 = fsub_rn_(__fadd_rn(fmb[1 * HW + nhw], 10.0f), c1);
                float d2 = fsub_rn_(__fadd_rn(fmb[2 * HW + nhw], 10.0f), c2);
                float ss = __fadd_rn(__fadd_rn(__fmul_rn(d0, d0), __fmul_rn(d1, d1)),
                                     __fmul_rn(d2, d2));
                float color = __fmul_rn(-ss, 2.0f);   // == __fdiv_rn(-ss,0.5f) exactly
                const float spk = __fdiv_rn(
                    (float)((ki - 1) * (ki - 1) + (kj - 1) * (kj - 1)), 1800.0f);
                wgt[k] = __fmul_rn(3.0f, expf(fsub_rn_(color, spk)));
            }
        }
    }
}

__device__ __forceinline__ unsigned mf_state72(const unsigned char* base,
                                               const float* w9, float tpx,
                                               float Lg45, float Lg55) {
    float a0 = 0.0f, a1 = 0.0f;
#pragma unroll
    for (int ki = 0; ki < 3; ++ki) {
#pragma unroll
        for (int kj = 0; kj < 3; ++kj) {
            const int k = ki * 3 + kj;
            unsigned char s = base[ki * SCB + kj];   // garbage when w9[k]==0 -> +0.0
            float u0 = (s & 1) ? Lg55 : Lg45;
            float u1 = (s & 2) ? Lg55 : Lg45;
            a0 = __fadd_rn(a0, __fmul_rn(u0, w9[k]));
            a1 = __fadd_rn(a1, __fmul_rn(u1, w9[k]));
        }
    }
    float f0 = expf(-a0);
    float f1 = __fmul_rn(expf(-a1), tpx);
    f0 = __fadd_rn(f0, 1e-6f);
    f1 = __fadd_rn(f1, 1e-6f);
    float S = __fadd_rn(f0, f1);
    float f0n = __fdiv_rn(f0, S);
    float f1n = __fdiv_rn(f1, S);
    return (f0n > 0.5f ? 1u : 0u) | (f1n > 0.5f ? 2u : 0u);
}

// ---- launch 1: per-pixel weights kern[b][k][HW] (21 MB) + s_0 init ----
__global__ __launch_bounds__(TPB) void precomp_kernel(
        const float* __restrict__ x, const float* __restrict__ t,
        const float* __restrict__ fm, float* __restrict__ kern,
        unsigned char* __restrict__ st0) {
    const int tid2 = blockIdx.x * TPB + threadIdx.x;
    const int p = tid2 * 2;                      // 2 px/thread
    const int b = p / HW, hw = p - b * HW;
    const int h = hw / Ww, w0 = hw - h * Ww;
    const float* fmb = fm + (size_t)b * 3 * HW;

    float wa[9], wb_[9];
    compute_weights(fmb, h, w0, hw, wa);
    compute_weights(fmb, h, w0 + 1, hw + 1, wb_);
    float* kb = kern + (size_t)b * 9 * HW + hw;
#pragma unroll
    for (int k = 0; k < 9; ++k)
        *reinterpret_cast<float2*>(kb + k * HW) = make_float2(wa[k], wb_[k]);

    float2 xv = reinterpret_cast<const float2*>(x)[tid2];
    float2 tv = reinterpret_cast<const float2*>(t)[tid2];
    unsigned short pack =
        (unsigned short)(((__fmul_rn(xv.x, tv.x) > 0.5f) ? 2u : 1u) |
                         (((__fmul_rn(xv.y, tv.y) > 0.5f) ? 2u : 1u) << 8));
    *reinterpret_cast<unsigned short*>(st0 + p) = pack;
}

// ---- stencil launch: 4 mean-field iterations via LDS shell pyramid ----
// Skip (r>0): staged cur-region == same region of nxt (holds s_{4r-4}) =>
// s_{4r+4} = s_{4r} and nxt already holds those bytes => skip compute+store.
// Compare is a superset of the math region -> false skips impossible.
template <bool FIRST, bool FIN>
__global__ __launch_bounds__(TPB) void stencil_kernel(
        const unsigned char* __restrict__ cur, unsigned char* __restrict__ nxt,
        const float* __restrict__ kern, const float* __restrict__ t,
        float* __restrict__ out, int* __restrict__ partial) {
    const int tid = threadIdx.x;
    const int bid = blockIdx.x;
    const int b = bid / BLKS_PER_B;
    const int rr_ = bid - b * BLKS_PER_B;
    const int ty = rr_ / TX, tx = rr_ - ty * TX;
    const int row0 = ty * TILE_H, col0 = tx * TILE_W;
    const int tr = tid >> 5;              // 0..7
    const int tc = (tid & 31) * 2;        // 0..62
    const int gp = b * HW + (row0 + tr) * Ww + col0 + tc;

    const float Lg45 = (float)(-log((double)0.45f));
    const float Lg55 = (float)(-log((double)0.55f));

    // ---- prologue: region weights/targets (L2/L3-resident kern) ----
    float sw[4][9];
    float stg[4];
    int svm = 0;
#pragma unroll
    for (int s = 0; s < 4; ++s) {
#pragma unroll
        for (int k = 0; k < 9; ++k) sw[s][k] = 0.0f;
        stg[s] = 0.0f;
        const int idx = tid + TPB * s;
        if (idx < REGN) {
            const int lr = 1 + idx / REG_W;
            const int lc = 1 + (idx - REG_W * (idx / REG_W));
            const int ir = row0 - 4 + lr, ic = col0 - 4 + lc;
            if (ir >= 0 && ir < Hh && ic >= 0 && ic < Ww) {
                svm |= 1 << s;
                const int phw = ir * Ww + ic;
#pragma unroll
                for (int k = 0; k < 9; ++k)
                    sw[s][k] = kern[((size_t)b * 9 + k) * HW + phw];
                stg[s] = t[(size_t)b * HW + phw];
            }
        }
    }

    __shared__ unsigned lds_cur[STOT];
    __shared__ unsigned char mA[SR * SCB];
    __shared__ unsigned char mB[SR * SCB];
    __shared__ int sconv[4];
    __shared__ int sred[4];

    // ---- stage cur region + compare vs nxt region ----
    bool eq = true;
    {
        const size_t roff = (size_t)b * HW + (row0 - 4) * Ww + (col0 - 4);
        for (int i = tid; i < STOT; i += TPB) {
            const int hr = i / SDW, hc = i - hr * SDW;
            const size_t byt = roff + hr * Ww + hc * 4;
            unsigned v = *reinterpret_cast<const unsigned*>(cur + byt);
            lds_cur[i] = v;
            if (!FIRST)
                eq = eq && (v == *reinterpret_cast<const unsigned*>(nxt + byt));
        }
    }
    {
        int ok = __all(eq);
        if ((tid & 63) == 0) sconv[tid >> 6] = ok;
    }
    __syncthreads();
    const bool skip =
        !FIRST && sconv[0] && sconv[1] && sconv[2] && sconv[3];

    const unsigned char* h2b = (const unsigned char*)lds_cur;
    unsigned n0 = 0, n1 = 0;

    if (!skip) {
        auto step = [&](const unsigned char* src, unsigned char* dst,
                        int rlo, int rhi, int clo, int chi) {
#pragma unroll
            for (int s = 0; s < 4; ++s) {
                const int idx = tid + TPB * s;
                if (idx < REGN && ((svm >> s) & 1)) {
                    const int lr = 1 + idx / REG_W;
                    const int lc = 1 + (idx - REG_W * (idx / REG_W));
                    if (lr >= rlo && lr <= rhi && lc >= clo && lc <= chi) {
                        unsigned m = mf_state72(src + (lr - 1) * SCB + (lc - 1),
                                                sw[s], stg[s], Lg45, Lg55);
                        dst[lr * SCB + lc] = (unsigned char)m;
                    }
                }
            }
        };
        step(h2b, mA, 1, 14, 1, 70);    // s_{4r+1} on 14x70
        __syncthreads();
        step(mA, mB, 2, 13, 2, 69);     // s_{4r+2} on 12x68
        __syncthreads();
        step(mB, mA, 3, 12, 3, 68);     // s_{4r+3} on 10x66
        __syncthreads();
        step(mA, mB, 4, 11, 4, 67);     // s_{4r+4} on own 8x64
        __syncthreads();
        n0 = mB[(4 + tr) * SCB + 4 + tc];
        n1 = mB[(4 + tr) * SCB + 5 + tc];
    } else {
        n0 = h2b[(4 + tr) * SCB + 4 + tc];
        n1 = h2b[(4 + tr) * SCB + 5 + tc];
    }

    if (FIN) {
        const float o0 = (n0 & 2) ? 1.0f : 0.0f;
        const float o1 = (n1 & 2) ? 1.0f : 0.0f;
        reinterpret_cast<float2*>(out)[gp >> 1] = make_float2(o0, o1);
        int cnt = (o0 != 0.0f) + (o1 != 0.0f);
        const int lane = tid & 63;
        const int wv = tid >> 6;
#pragma unroll
        for (int off = 32; off; off >>= 1) cnt += __shfl_down(cnt, off, 64);
        if (lane == 0) sred[wv] = cnt;
        __syncthreads();
        if (tid == 0)
            partial[bid] = sred[0] + sred[1] + sred[2] + sred[3];
    } else {
        if (!skip)
            *reinterpret_cast<unsigned short*>(nxt + gp) =
                (unsigned short)(n0 | (n1 << 8));
    }
}

__global__ void valid_kernel(const int* __restrict__ partial,
                             float* __restrict__ outv) {
    const int tid = threadIdx.x;
    const int wv = tid >> 6;          // batch 0..3
    const int lane = tid & 63;
    const int base = wv * BLKS_PER_B; // 288 partials per batch = 4x64 + 32
    int s = 0;
#pragma unroll
    for (int k = 0; k < 4; ++k) s += partial[base + 64 * k + lane];
    if (lane < 32) s += partial[base + 256 + lane];
#pragma unroll
    for (int off = 32; off; off >>= 1) s += __shfl_down(s, off, 64);
    if (lane == 0) {
        float cf = (float)s;
        const float lo = (float)(147456.0 * 0.05);
        const float hi = (float)(147456.0 * 0.95);
        outv[wv] = (cf >= lo && cf <= hi) ? 1.0f : 0.0f;
    }
}

}  // namespace

extern "C" void kernel_launch(void* const* d_in, const int* in_sizes, int n_in,
                              void* d_out, int out_size, void* d_ws, size_t ws_size,
                              hipStream_t stream) {
    const float* x  = (const float*)d_in[0];
    const float* tg = (const float*)d_in[1];
    const float* fm = (const float*)d_in[2];
    float* out = (float*)d_out;

    char* ws = (char*)d_ws;
    // layout (bytes):
    //   partial: 0      .. 4608     (1152 x 4)
    //   pad    : 4608   .. 16384    (static -> top-overhang reads deterministic*)
    //   st0    : 16384  .. 606208
    //   pad    : 2048   (static -> bottom-overhang safe)
    //   st1    : 608256 .. 1198080
    //   pad    : -> 1198592 .. 1200128
    //   kern   : 1200128 .. +21233664 (4 x 9 x HW f32, ~21.2 MB)
    // (*) partial bytes can race with FIN staging reads: harmless — compared
    //     bytes are a superset; mismatches only disable skip, results exact.
    int* partial = (int*)ws;
    unsigned char* st0 = (unsigned char*)(ws + 16384);
    unsigned char* st1 = st0 + NPIX + 2048;
    float* kern = (float*)(ws + 1200128);

    precomp_kernel<<<NPIX / (TPB * 2), TPB, 0, stream>>>(x, tg, fm, kern, st0);
    // 5 launches x 4 iterations: s_0 ->s_4 ->s_8 ->s_12 ->s_16 ->(FIN) s_20
    stencil_kernel<true,  false><<<NBLK, TPB, 0, stream>>>(st0, st1, kern, tg, out, partial);
    stencil_kernel<false, false><<<NBLK, TPB, 0, stream>>>(st1, st0, kern, tg, out, partial);
    stencil_kernel<false, false><<<NBLK, TPB, 0, stream>>>(st0, st1, kern, tg, out, partial);
    stencil_kernel<false, false><<<NBLK, TPB, 0, stream>>>(st1, st0, kern, tg, out, partial);
    stencil_kernel<false, true ><<<NBLK, TPB, 0, stream>>>(st0, st1, kern, tg, out, partial);
    valid_kernel<<<1, 256, 0, stream>>>(partial, out + NPIX);
}

// Round 13
// 102.007 us; speedup vs baseline: 1.1708x; 1.1708x over previous
//
#include <hip/hip_runtime.h>
#include <math.h>

namespace {

constexpr int Hh = 384;
constexpr int Ww = 384;
constexpr int Bb = 4;
constexpr int HW = Hh * Ww;          // 147456
constexpr int NPIX = Bb * HW;        // 589824
constexpr int ROUNDS = 5;            // 4 mean-field iterations per round
constexpr int TPB = 256;

constexpr int TILE_W = 64;
constexpr int TILE_H = 8;
constexpr int TX = Ww / TILE_W;              // 6
constexpr int TY = Hh / TILE_H;              // 48
constexpr int BLKS_PER_B = TX * TY;          // 288
constexpr int NBLK = Bb * BLKS_PER_B;        // 1152

// width-4 halo staged per round: rows row0-4..row0+11 (16), col bytes col0-4..col0+67 (72)
constexpr int SR = 16;
constexpr int SCB = 72;
constexpr int SDW = SCB / 4;                 // 18 dwords/row
constexpr int STOT = SR * SDW;               // 288 dwords

// shell region: local coords lr 1..14, lc 1..70
constexpr int REG_W = 70;
constexpr int REGN = 14 * REG_W;             // 980 pixels

__device__ __forceinline__ float fsub_rn_(float a, float b) {
    return __fadd_rn(a, -b);
}

__device__ __forceinline__ unsigned ld_agent_u32(const void* p) {
    return __hip_atomic_load((const unsigned*)p, __ATOMIC_RELAXED,
                             __HIP_MEMORY_SCOPE_AGENT);
}
__device__ __forceinline__ void st_agent_u16(void* p, unsigned short v) {
    __hip_atomic_store((unsigned short*)p, v, __ATOMIC_RELAXED,
                       __HIP_MEMORY_SCOPE_AGENT);
}
__device__ __forceinline__ int ld_agent_i32(const int* p) {
    return __hip_atomic_load(p, __ATOMIC_RELAXED, __HIP_MEMORY_SCOPE_AGENT);
}
__device__ __forceinline__ void st_agent_i32(int* p, int v) {
    __hip_atomic_store(p, v, __ATOMIC_RELAXED, __HIP_MEMORY_SCOPE_AGENT);
}

// 9 pairwise weights for pixel (h,w); /0.5 folded to *2.0 (exact, bit-identical)
__device__ __forceinline__ void compute_weights(const float* __restrict__ fmb,
                                                int h, int w, int hw,
                                                float* __restrict__ wgt) {
    float c0 = __fadd_rn(fmb[0 * HW + hw], 10.0f);
    float c1 = __fadd_rn(fmb[1 * HW + hw], 10.0f);
    float c2 = __fadd_rn(fmb[2 * HW + hw], 10.0f);
#pragma unroll
    for (int ki = 0; ki < 3; ++ki) {
#pragma unroll
        for (int kj = 0; kj < 3; ++kj) {
            const int k = ki * 3 + kj;
            const int hh = h + ki - 1;
            const int ww2 = w + kj - 1;
            if (hh < 0 || hh >= Hh || ww2 < 0 || ww2 >= Ww) {
                wgt[k] = 0.0f;   // OOB taps contribute exact +0.0
            } else {
                const int nhw = hh * Ww + ww2;
                float d0 = fsub_rn_(__fadd_rn(fmb[0 * HW + nhw], 10.0f), c0);
                float d1 = fsub_rn_(__fadd_rn(fmb[1 * HW + nhw], 10.0f), c1);
                float d2 = fsub_rn_(__fadd_rn(fmb[2 * HW + nhw], 10.0f), c2);
                float ss = __fadd_rn(__fadd_rn(__fmul_rn(d0, d0), __fmul_rn(d1, d1)),
                                     __fmul_rn(d2, d2));
                float color = __fmul_rn(-ss, 2.0f);   // == __fdiv_rn(-ss,0.5f) exactly
                const float spk = __fdiv_rn(
                    (float)((ki - 1) * (ki - 1) + (kj - 1) * (kj - 1)), 1800.0f);
                wgt[k] = __fmul_rn(3.0f, expf(fsub_rn_(color, spk)));
            }
        }
    }
}

// exact reference chain (cold path) — byte-identical to the proven kernels
__device__ __forceinline__ unsigned mf_exact72(const unsigned char* base,
                                               const float* w9, float tpx,
                                               float Lg45, float Lg55) {
    float a0 = 0.0f, a1 = 0.0f;
#pragma unroll
    for (int ki = 0; ki < 3; ++ki) {
#pragma unroll
        for (int kj = 0; kj < 3; ++kj) {
            const int k = ki * 3 + kj;
            unsigned char s = base[ki * SCB + kj];
            float u0 = (s & 1) ? Lg55 : Lg45;
            float u1 = (s & 2) ? Lg55 : Lg45;
            a0 = __fadd_rn(a0, __fmul_rn(u0, w9[k]));
            a1 = __fadd_rn(a1, __fmul_rn(u1, w9[k]));
        }
    }
    float f0 = expf(-a0);
    float f1 = __fmul_rn(expf(-a1), tpx);
    f0 = __fadd_rn(f0, 1e-6f);
    f1 = __fadd_rn(f1, 1e-6f);
    float S = __fadd_rn(f0, f1);
    float f0n = __fdiv_rn(f0, S);
    float f1n = __fdiv_rn(f1, S);
    return (f0n > 0.5f ? 1u : 0u) | (f1n > 0.5f ? 2u : 0u);
}

// Sync/skip/gdone structure identical to R10 (proven). Only the per-pixel
// update inside `step` changed: exact fast-path discriminant.
//   g = DD*(A0-A1) + ln t  where A_c = sum of w_k over taps with bit c set.
//   sign(f1n-0.5) == sign(g); reference rounding band |f1n-0.5| <= ~1e-6;
//   |f1n-0.5| >= |g|/5 while S is not 1e-6-floor-dominated (a0 < 11.5).
//   Fast iff |g| > 3.25e-4 && a0 < 11.5 (eval err <= 2e-5, 15x slack),
//   else cold exact chain. Bit-exact in all regimes.
__global__ __launch_bounds__(TPB, 5) void fused_kernel(
        const float* __restrict__ x, const float* __restrict__ t,
        const float* __restrict__ fm, float* __restrict__ out,
        int* __restrict__ arrive, int* __restrict__ flags,
        int* __restrict__ conv, int* __restrict__ partial,
        unsigned char* __restrict__ st0, unsigned char* __restrict__ st1) {
    const int tid = threadIdx.x;
    const int bid = blockIdx.x;
    const int b = bid / BLKS_PER_B;
    const int rr_ = bid - b * BLKS_PER_B;
    const int ty = rr_ / TX, tx = rr_ - ty * TX;
    const int row0 = ty * TILE_H, col0 = tx * TILE_W;
    const int tr = tid >> 5;              // 0..7
    const int tc = (tid & 31) * 2;        // 0..62
    const int gp = b * HW + (row0 + tr) * Ww + col0 + tc;

    bool nactive = false;
    const int* nflag = nullptr;
    if (tid < 8) {
        const int l2 = (tid < 4) ? tid : tid + 1;
        const int dy = l2 / 3 - 1, dx = l2 - (l2 / 3) * 3 - 1;
        const int nty = ty + dy, ntx = tx + dx;
        if (nty >= 0 && nty < TY && ntx >= 0 && ntx < TX) {
            nactive = true;
            nflag = &flags[(b * BLKS_PER_B + nty * TX + ntx) << 4];
        }
    }

    const float Lg45 = (float)(-log((double)0.45f));
    const float Lg55 = (float)(-log((double)0.55f));
    const float DD = (float)(log((double)0.45f) - log((double)0.55f)); // -0.2007
    const float GM = 3.25e-4f;

    // ---- once: weights, targets, ln t, L45*sum(w) per region slot ----
    const float* fmb = fm + (size_t)b * 3 * HW;
    float sw[4][9];
    float stg[4], slnt[4], sA0b[4];
    int svm = 0;
#pragma unroll
    for (int s = 0; s < 4; ++s) {
        const int idx = tid + TPB * s;
#pragma unroll
        for (int k = 0; k < 9; ++k) sw[s][k] = 0.0f;
        stg[s] = 0.0f; slnt[s] = 0.0f; sA0b[s] = 0.0f;
        if (idx < REGN) {
            const int lr = 1 + idx / REG_W;
            const int lc = 1 + (idx - REG_W * (idx / REG_W));
            const int ir = row0 - 4 + lr, ic = col0 - 4 + lc;
            if (ir >= 0 && ir < Hh && ic >= 0 && ic < Ww) {
                svm |= 1 << s;
                compute_weights(fmb, ir, ic, ir * Ww + ic, sw[s]);
                stg[s] = t[(size_t)b * HW + ir * Ww + ic];
                slnt[s] = logf(stg[s]);
                float Wsum = 0.0f;
#pragma unroll
                for (int k = 0; k < 9; ++k) Wsum += sw[s][k];
                sA0b[s] = Lg45 * Wsum;
            }
        }
    }

    // init state for own 2 px
    {
        float2 xv = reinterpret_cast<const float2*>(x)[gp >> 1];
        float2 tv = reinterpret_cast<const float2*>(t)[gp >> 1];
        unsigned short pack =
            (unsigned short)(((__fmul_rn(xv.x, tv.x) > 0.5f) ? 2u : 1u) |
                             (((__fmul_rn(xv.y, tv.y) > 0.5f) ? 2u : 1u) << 8));
        st_agent_u16(st0 + gp, pack);
    }

    __shared__ unsigned lds_h2[2][STOT];
    __shared__ unsigned char mA[SR * SCB];
    __shared__ unsigned char mB[SR * SCB];
    __shared__ int sconv[4];
    __shared__ int sred[4];
    __shared__ int sdone;

    for (int i = tid; i < STOT; i += TPB) lds_h2[1][i] = 0xFFFFFFFFu;
    __syncthreads();                      // drain s_0 stores (vmcnt 0)
    if (tid == 0) st_agent_i32(&flags[bid << 4], 1);

    auto step = [&](const unsigned char* src, unsigned char* dst,
                    int rlo, int rhi, int clo, int chi) {
#pragma unroll
        for (int s = 0; s < 4; ++s) {
            const int idx = tid + TPB * s;
            if (idx < REGN && ((svm >> s) & 1)) {
                const int lr = 1 + idx / REG_W;
                const int lc = 1 + (idx - REG_W * (idx / REG_W));
                if (lr >= rlo && lr <= rhi && lc >= clo && lc <= chi) {
                    const unsigned char* base = src + (lr - 1) * SCB + (lc - 1);
                    float A0 = 0.0f, A1 = 0.0f;
#pragma unroll
                    for (int ki = 0; ki < 3; ++ki) {
#pragma unroll
                        for (int kj = 0; kj < 3; ++kj) {
                            const int k = ki * 3 + kj;
                            unsigned char sbyte = base[ki * SCB + kj];
                            A0 = __fadd_rn(A0, (sbyte & 1) ? sw[s][k] : 0.0f);
                            A1 = __fadd_rn(A1, (sbyte & 2) ? sw[s][k] : 0.0f);
                        }
                    }
                    const float g = __fmaf_rn(DD, fsub_rn_(A0, A1), slnt[s]);
                    const float a0f = __fmaf_rn(DD, A0, sA0b[s]);
                    unsigned m;
                    if (__builtin_expect(fabsf(g) > GM && a0f < 11.5f, 1)) {
                        m = (g > 0.0f) ? 2u : 1u;
                    } else {
                        m = mf_exact72(base, sw[s], stg[s], Lg45, Lg55);
                    }
                    dst[lr * SCB + lc] = (unsigned char)m;
                }
            }
        }
    };

    unsigned n0 = 0, n1 = 0;

    for (int r = 0; r < ROUNDS; ++r) {
        const bool fin = (r == ROUNDS - 1);
        const int hbuf = r & 1;
        const unsigned char* cur = (r & 1) ? st1 : st0;
        unsigned char* nxt = (r & 1) ? st0 : st1;

        if (r >= 2) {
            int v = 0;
            if (tid < 16) v = ld_agent_i32(&conv[((r - 1) * 16 + tid) << 4]);
            if (tid < 64) {
#pragma unroll
                for (int off = 1; off < 64; off <<= 1) v += __shfl_xor(v, off, 64);
                if (tid == 0) sdone = (v >= NBLK);
            }
            __syncthreads();
            const bool gdone = (sdone != 0);
            if (gdone) {
                if (tid == 0) st_agent_i32(&flags[bid << 4], ROUNDS + 2);
                const unsigned char* hb =
                    (const unsigned char*)lds_h2[(r - 1) & 1];
                n0 = hb[(4 + tr) * SCB + 4 + tc];
                n1 = hb[(4 + tr) * SCB + 5 + tc];
                break;
            }
        }

        if (tid < 64) {
            const int target = r + 1;
            for (;;) {
                bool ok = true;
                if (nactive) ok = (ld_agent_i32(nflag) >= target);
                if (__all(ok)) break;
                __builtin_amdgcn_s_sleep(1);
            }
        }
        __syncthreads();

        bool eq = true;
        {
            const unsigned char* base2 =
                cur + (size_t)b * HW + (row0 - 4) * Ww + (col0 - 4);
            for (int i = tid; i < STOT; i += TPB) {
                const int hr = i / SDW, hc = i - hr * SDW;
                unsigned vv = ld_agent_u32(base2 + hr * Ww + hc * 4);
                eq = eq && (vv == lds_h2[hbuf ^ 1][i]);
                lds_h2[hbuf][i] = vv;
            }
        }
        {
            int ok = __all(eq);
            if ((tid & 63) == 0) sconv[tid >> 6] = ok;
        }
        __syncthreads();
        const bool skip =
            (r > 0) && sconv[0] && sconv[1] && sconv[2] && sconv[3];

        const unsigned char* h2b = (const unsigned char*)lds_h2[hbuf];
        if (skip) {
            if (tid == 0)
                __hip_atomic_fetch_add(&conv[(r * 16 + (bid & 15)) << 4], 1,
                                       __ATOMIC_RELAXED, __HIP_MEMORY_SCOPE_AGENT);
            n0 = h2b[(4 + tr) * SCB + 4 + tc];
            n1 = h2b[(4 + tr) * SCB + 5 + tc];
        } else {
            step(h2b, mA, 1, 14, 1, 70);    // s_{4r+1} on 14x70
            __syncthreads();
            step(mA, mB, 2, 13, 2, 69);     // s_{4r+2} on 12x68
            __syncthreads();
            step(mB, mA, 3, 12, 3, 68);     // s_{4r+3} on 10x66
            __syncthreads();
            step(mA, mB, 4, 11, 4, 67);     // s_{4r+4} on own 8x64
            __syncthreads();
            n0 = mB[(4 + tr) * SCB + 4 + tc];
            n1 = mB[(4 + tr) * SCB + 5 + tc];
        }

        if (!fin) {
            if (!skip) {
                st_agent_u16(nxt + gp, (unsigned short)(n0 | (n1 << 8)));
                __syncthreads();          // drain s_{4r+4} stores
            }
            if (tid == 0) st_agent_i32(&flags[bid << 4], r + 2);
        }
    }

    const float o0 = (n0 & 2) ? 1.0f : 0.0f;
    const float o1 = (n1 & 2) ? 1.0f : 0.0f;
    reinterpret_cast<float2*>(out)[gp >> 1] = make_float2(o0, o1);
    {
        int cnt = (o0 != 0.0f) + (o1 != 0.0f);
        const int lane = tid & 63;
        const int wv = tid >> 6;
#pragma unroll
        for (int off = 32; off; off >>= 1) cnt += __shfl_down(cnt, off, 64);
        if (lane == 0) sred[wv] = cnt;
    }
    __syncthreads();
    if (tid == 0) {
        int tot = sred[0] + sred[1] + sred[2] + sred[3];
        st_agent_i32(&partial[bid], tot);
    }
    __syncthreads();
    if (tid == 0)
        __hip_atomic_fetch_add(&arrive[(bid & 15) << 4], 1,
                               __ATOMIC_RELAXED, __HIP_MEMORY_SCOPE_AGENT);
    if (bid == 0) {
        if (tid < 64) {
            for (;;) {
                int v = 0;
                if (tid < 16) v = ld_agent_i32(&arrive[tid << 4]);
#pragma unroll
                for (int off = 1; off < 64; off <<= 1) v += __shfl_xor(v, off, 64);
                if (v >= NBLK) break;
                __builtin_amdgcn_s_sleep(1);
            }
        }
        __syncthreads();
        const int wv = tid >> 6;
        const int lane = tid & 63;
        const int base = wv * BLKS_PER_B;
        int s = 0;
#pragma unroll
        for (int k = 0; k < 4; ++k) s += ld_agent_i32(&partial[base + 64 * k + lane]);
        if (lane < 32) s += ld_agent_i32(&partial[base + 256 + lane]);
#pragma unroll
        for (int off = 32; off; off >>= 1) s += __shfl_down(s, off, 64);
        if (lane == 0) {
            float cf = (float)s;
            const float lo = (float)(147456.0 * 0.05);
            const float hi = (float)(147456.0 * 0.95);
            out[NPIX + wv] = (cf >= lo && cf <= hi) ? 1.0f : 0.0f;
        }
    }
}

}  // namespace

extern "C" void kernel_launch(void* const* d_in, const int* in_sizes, int n_in,
                              void* d_out, int out_size, void* d_ws, size_t ws_size,
                              hipStream_t stream) {
    const float* x  = (const float*)d_in[0];
    const float* tg = (const float*)d_in[1];
    const float* fm = (const float*)d_in[2];
    float* out = (float*)d_out;

    char* ws = (char*)d_ws;
    // layout (bytes) — identical to R10:
    //   arrive : 0      .. 1024
    //   flags  : 1024   .. 74752     (1152 x 64B)
    //   conv   : 74752  .. 79872     (5 rounds x 16 stripes x 64B)
    //   partial: 79872  .. 84480
    //   pad    : 84480  .. 86528     (static -> halo overhang safe)
    //   st0    : 86528  .. +NPIX
    //   pad    : 2048
    //   st1    : .. +NPIX
    int* arrive  = (int*)ws;
    int* flags   = (int*)(ws + 1024);
    int* conv    = (int*)(ws + 74752);
    int* partial = (int*)(ws + 79872);
    unsigned char* st0 = (unsigned char*)(ws + 86528);
    unsigned char* st1 = st0 + NPIX + 2048;

    // zero arrive + flags + conv every call (graph-captured)
    (void)hipMemsetAsync(ws, 0, 79872, stream);

    fused_kernel<<<NBLK, TPB, 0, stream>>>(x, tg, fm, out, arrive, flags,
                                           conv, partial, st0, st1);
}

// Round 14
// 70.397 us; speedup vs baseline: 1.6966x; 1.4490x over previous
//
#include <hip/hip_runtime.h>
#include <math.h>

namespace {

constexpr int Hh = 384;
constexpr int Ww = 384;
constexpr int Bb = 4;
constexpr int HW = Hh * Ww;          // 147456
constexpr int NPIX = Bb * HW;        // 589824
constexpr int ROUNDS = 10;           // 2 mean-field iterations per round
constexpr int TPB = 256;

// 2D tiling: each block owns a 64x8 tile (2 px/thread), 6x48 tiles/batch
constexpr int TILE_W = 64;
constexpr int TILE_H = 8;
constexpr int TX = Ww / TILE_W;              // 6
constexpr int TY = Hh / TILE_H;              // 48
constexpr int BLKS_PER_B = TX * TY;          // 288
constexpr int NBLK = Bb * BLKS_PER_B;        // 1152

// width-2 halo staged per compute round: rows row0-2..row0+9 (12), cols col0-8..col0+71 (80 B)
constexpr int H2ROWS = 12;
constexpr int H2DW = 20;                     // 80 B / 4
constexpr int H2TOT = H2ROWS * H2DW;         // 240 dwords

// intermediate s_{2r+1}: extended region rows row0-1..row0+8 (10) x cols col0-1..col0+64 (66)
constexpr int MIDS = 68;                     // byte stride
constexpr int NRING = 148;                   // ring pixels of the 10x66 region

__device__ __forceinline__ float fsub_rn_(float a, float b) {
    return __fadd_rn(a, -b);
}

__device__ __forceinline__ unsigned ld_agent_u32(const void* p) {
    return __hip_atomic_load((const unsigned*)p, __ATOMIC_RELAXED,
                             __HIP_MEMORY_SCOPE_AGENT);
}
__device__ __forceinline__ void st_agent_u16(void* p, unsigned short v) {
    __hip_atomic_store((unsigned short*)p, v, __ATOMIC_RELAXED,
                       __HIP_MEMORY_SCOPE_AGENT);
}
__device__ __forceinline__ int ld_agent_i32(const int* p) {
    return __hip_atomic_load(p, __ATOMIC_RELAXED, __HIP_MEMORY_SCOPE_AGENT);
}
__device__ __forceinline__ void st_agent_i32(int* p, int v) {
    __hip_atomic_store(p, v, __ATOMIC_RELAXED, __HIP_MEMORY_SCOPE_AGENT);
}

// 9 pairwise weights for pixel (h,w); /0.5 folded to *2.0 (exact, bit-identical)
__device__ __forceinline__ void compute_weights(const float* __restrict__ fmb,
                                                int h, int w, int hw,
                                                float* __restrict__ wgt) {
    float c0 = __fadd_rn(fmb[0 * HW + hw], 10.0f);
    float c1 = __fadd_rn(fmb[1 * HW + hw], 10.0f);
    float c2 = __fadd_rn(fmb[2 * HW + hw], 10.0f);
#pragma unroll
    for (int ki = 0; ki < 3; ++ki) {
#pragma unroll
        for (int kj = 0; kj < 3; ++kj) {
            const int k = ki * 3 + kj;
            const int hh = h + ki - 1;
            const int ww2 = w + kj - 1;
            if (hh < 0 || hh >= Hh || ww2 < 0 || ww2 >= Ww) {
                wgt[k] = 0.0f;   // OOB taps contribute exact +0.0
            } else {
                const int nhw = hh * Ww + ww2;
                float d0 = fsub_rn_(__fadd_rn(fmb[0 * HW + nhw], 10.0f), c0);
                float d1 = fsub_rn_(__fadd_rn(fmb[1 * HW + nhw], 10.0f), c1);
                float d2 = fsub_rn_(__fadd_rn(fmb[2 * HW + nhw], 10.0f), c2);
                float ss = __fadd_rn(__fadd_rn(__fmul_rn(d0, d0), __fmul_rn(d1, d1)),
                                     __fmul_rn(d2, d2));
                float color = __fmul_rn(-ss, 2.0f);   // == __fdiv_rn(-ss,0.5f) exactly
                const float spk = __fdiv_rn(
                    (float)((ki - 1) * (ki - 1) + (kj - 1) * (kj - 1)), 1800.0f);
                wgt[k] = __fmul_rn(3.0f, expf(fsub_rn_(color, spk)));
            }
        }
    }
}

// one mean-field pixel update; base -> top-left tap. FP order identical to ref.
template <int STRIDE>
__device__ __forceinline__ unsigned mf_state(const unsigned char* base,
                                             const float* w9, float tpx,
                                             float Lg45, float Lg55) {
    float a0 = 0.0f, a1 = 0.0f;
#pragma unroll
    for (int ki = 0; ki < 3; ++ki) {
#pragma unroll
        for (int kj = 0; kj < 3; ++kj) {
            const int k = ki * 3 + kj;
            unsigned char s = base[ki * STRIDE + kj];   // garbage when w9[k]==0 -> +0.0
            float u0 = (s & 1) ? Lg55 : Lg45;
            float u1 = (s & 2) ? Lg55 : Lg45;
            a0 = __fadd_rn(a0, __fmul_rn(u0, w9[k]));
            a1 = __fadd_rn(a1, __fmul_rn(u1, w9[k]));
        }
    }
    float f0 = expf(-a0);
    float f1 = __fmul_rn(expf(-a1), tpx);
    f0 = __fadd_rn(f0, 1e-6f);
    f1 = __fadd_rn(f1, 1e-6f);
    float S = __fadd_rn(f0, f1);
    float f0n = __fdiv_rn(f0, S);
    float f1n = __fdiv_rn(f1, S);
    return (f0n > 0.5f ? 1u : 0u) | (f1n > 0.5f ? 2u : 0u);
}

__device__ __forceinline__ void ring_coords(int ri, int& er, int& ec) {
    if (ri < 66)       { er = 0;        ec = ri; }
    else if (ri < 132) { er = 9;        ec = ri - 66; }
    else if (ri < 140) { er = ri - 131; ec = 0; }     // 1..8
    else               { er = ri - 139; ec = 65; }    // 1..8
}

// Flag word: ((q+2)<<2) | (changed_q<<1) | changed_{q-1}, published at end of
// round q (changed_q = own 8x64 tile differs from its round-q input).
// Round r waits all 9 (self implicit) parts >= r+1; skew bound 1 => part is
// r+1 (take bit1) or r+2 (take bit0) for changed_{r-1}.
// skip_r = (r>0) && all-9 changed_{r-1}==0: region s_{2r} == s_{2r-2}, LDS
// still current (induction over skip/stage), outputs = staged own bytes,
// no stage/store needed. Buffer staleness impossible: changed=1 forces self
// and all neighbors to compute next round, refreshing the other parity.
__global__ __launch_bounds__(TPB, 8) void fused_kernel(
        const float* __restrict__ x, const float* __restrict__ t,
        const float* __restrict__ fm, float* __restrict__ out,
        int* __restrict__ arrive, int* __restrict__ flags,
        int* __restrict__ partial,
        unsigned char* __restrict__ st0, unsigned char* __restrict__ st1) {
    const int tid = threadIdx.x;
    const int bid = blockIdx.x;
    const int b = bid / BLKS_PER_B;
    const int rr_ = bid - b * BLKS_PER_B;
    const int ty = rr_ / TX, tx = rr_ - ty * TX;
    const int row0 = ty * TILE_H, col0 = tx * TILE_W;
    const int tr = tid >> 5;              // 0..7
    const int tc = (tid & 31) * 2;        // 0..62
    const int row = row0 + tr, col = col0 + tc;
    const int hw = row * Ww + col;
    const int gp = b * HW + hw;           // gp % 2 == 0

    // lanes 0..7 of wave 0 poll one neighbor each
    bool nactive = false;
    const int* nflag = nullptr;
    if (tid < 8) {
        const int l2 = (tid < 4) ? tid : tid + 1;       // skip center
        const int dy = l2 / 3 - 1, dx = l2 - (l2 / 3) * 3 - 1;
        const int nty = ty + dy, ntx = tx + dx;
        if (nty >= 0 && nty < TY && ntx >= 0 && ntx < TX) {
            nactive = true;
            nflag = &flags[(b * BLKS_PER_B + nty * TX + ntx) << 4];
        }
    }

    const float Lg45 = (float)(-log((double)0.45f));
    const float Lg55 = (float)(-log((double)0.55f));

    // ---- once: own weights+targets, ring weights+targets, init state ----
    const float* fmb = fm + (size_t)b * 3 * HW;
    float wall[2][9];
#pragma unroll
    for (int j = 0; j < 2; ++j)
        compute_weights(fmb, row, col + j, hw + j, wall[j]);

    bool ringv = false;
    int rer = 0, rec = 0;
    float rw[9] = {0, 0, 0, 0, 0, 0, 0, 0, 0};
    float rt = 0.0f;
    if (tid < NRING) {
        ring_coords(tid, rer, rec);
        const int irow = row0 - 1 + rer, icol = col0 - 1 + rec;
        ringv = (irow >= 0 && irow < Hh && icol >= 0 && icol < Ww);
        if (ringv) {
            compute_weights(fmb, irow, icol, irow * Ww + icol, rw);
            rt = t[(size_t)b * HW + irow * Ww + icol];
        }
    }

    float2 xv = reinterpret_cast<const float2*>(x)[gp >> 1];
    float2 tv = reinterpret_cast<const float2*>(t)[gp >> 1];
    const float tj[2] = {tv.x, tv.y};
    {
        unsigned short pack =
            (unsigned short)(((__fmul_rn(xv.x, tv.x) > 0.5f) ? 2u : 1u) |
                             (((__fmul_rn(xv.y, tv.y) > 0.5f) ? 2u : 1u) << 8));
        st_agent_u16(st0 + gp, pack);
    }
    __syncthreads();                      // drain s_0 stores (vmcnt 0)
    // part 1 ("s_0 visible"), changed bits 1 (round 0 never skips anyway)
    if (tid == 0) st_agent_i32(&flags[bid << 4], (1 << 2) | 3);

    __shared__ unsigned lds_h2[H2TOT];            // staged region (single buffer)
    __shared__ unsigned char lds_mid[10 * MIDS];  // s_{2r+1}, 10x66 used
    __shared__ int sskip;
    __shared__ int schg[4];
    __shared__ int sred[4];

    int pchg = 1;                          // changed_{r-1}, block-uniform

    // ---- 10 rounds x 2 iterations ----
    for (int r = 0; r < ROUNDS; ++r) {
        const bool fin = (r == ROUNDS - 1);
        const unsigned char* cur = (r & 1) ? st1 : st0;
        unsigned char* nxt = (r & 1) ? st0 : st1;

        // poll: all neighbors part >= r+1; capture their changed_{r-1}
        if (tid < 64) {
            int nchg = 0;
            for (;;) {
                bool ok = true;
                if (nactive) {
                    int f = ld_agent_i32(nflag);
                    int part = f >> 2;
                    ok = (part >= r + 1);
                    if (ok) nchg = (part == r + 1) ? ((f >> 1) & 1) : (f & 1);
                }
                if (__all(ok)) break;
                __builtin_amdgcn_s_sleep(1);
            }
            bool unch = nactive ? (nchg == 0) : true;
            int au = __all(unch);
            if (tid == 0) sskip = au;
        }
        __syncthreads();
        const bool skip = (r > 0) && (sskip != 0) && (pchg == 0);

        const unsigned char* h2b = (const unsigned char*)lds_h2;
        unsigned n2[2];
        int chg;

        if (skip) {
            // region s_{2r} == LDS content; outputs = inputs; nothing stored
            n2[0] = h2b[(tr + 2) * 80 + tc + 8];
            n2[1] = h2b[(tr + 2) * 80 + tc + 9];
            chg = 0;
            if (!fin && tid == 0)
                st_agent_i32(&flags[bid << 4], ((r + 2) << 2) | (0 << 1) | pchg);
        } else {
            // stage width-2 halo: rows row0-2..row0+9, col bytes col0-8..col0+71
            if (tid < H2TOT) {
                const unsigned char* base2 =
                    cur + (size_t)b * HW + (row0 - 2) * Ww + (col0 - 8);
                const int hr = tid / H2DW, hc = tid - hr * H2DW;
                lds_h2[tid] = ld_agent_u32(base2 + hr * Ww + hc * 4);
            }
            __syncthreads();

            // step 1: s_{2r+1} on extended 10x66 region into lds_mid
#pragma unroll
            for (int j = 0; j < 2; ++j) {
                unsigned m = mf_state<80>(h2b + (tr + 1) * 80 + tc + 7 + j,
                                          wall[j], tj[j], Lg45, Lg55);
                lds_mid[(tr + 1) * MIDS + tc + j + 1] = (unsigned char)m;
            }
            if (ringv) {
                unsigned m = mf_state<80>(h2b + rer * 80 + rec + 6,
                                          rw, rt, Lg45, Lg55);
                lds_mid[rer * MIDS + rec] = (unsigned char)m;
            }
            __syncthreads();

            // step 2: s_{2r+2} for own 2 px from lds_mid
#pragma unroll
            for (int j = 0; j < 2; ++j)
                n2[j] = mf_state<MIDS>(lds_mid + tr * MIDS + tc + j,
                                       wall[j], tj[j], Lg45, Lg55);

            // changed detection vs staged own bytes
            bool diff = (n2[0] != (unsigned)h2b[(tr + 2) * 80 + tc + 8]) ||
                        (n2[1] != (unsigned)h2b[(tr + 2) * 80 + tc + 9]);
            {
                int any = __any(diff);
                if ((tid & 63) == 0) schg[tid >> 6] = any;
            }
            if (!fin)
                st_agent_u16(nxt + gp, (unsigned short)(n2[0] | (n2[1] << 8)));
            __syncthreads();              // drains state stores + schg writes
            chg = (schg[0] | schg[1] | schg[2] | schg[3]) ? 1 : 0;
            if (!fin && tid == 0)
                st_agent_i32(&flags[bid << 4], ((r + 2) << 2) | (chg << 1) | pchg);
        }
        pchg = chg;

        if (fin) {
            const float o0 = (n2[0] & 2) ? 1.0f : 0.0f;
            const float o1 = (n2[1] & 2) ? 1.0f : 0.0f;
            reinterpret_cast<float2*>(out)[gp >> 1] = make_float2(o0, o1);
            int cnt = (o0 != 0.0f) + (o1 != 0.0f);
            const int lane = tid & 63;
            const int wv = tid >> 6;
#pragma unroll
            for (int off = 32; off; off >>= 1) cnt += __shfl_down(cnt, off, 64);
            if (lane == 0) sred[wv] = cnt;
            __syncthreads();
            if (tid == 0) {
                int tot = sred[0] + sred[1] + sred[2] + sred[3];
                st_agent_i32(&partial[bid], tot);
            }
        }
    }

    // ---- final global sync (partials), then block 0 reduces -> valid ----
    __syncthreads();                      // drain partial store
    if (tid == 0)
        __hip_atomic_fetch_add(&arrive[(bid & 15) << 4], 1,
                               __ATOMIC_RELAXED, __HIP_MEMORY_SCOPE_AGENT);
    if (bid == 0) {
        if (tid < 64) {
            for (;;) {
                int v = 0;
                if (tid < 16) v = ld_agent_i32(&arrive[tid << 4]);
#pragma unroll
                for (int off = 1; off < 64; off <<= 1) v += __shfl_xor(v, off, 64);
                if (v >= NBLK) break;
                __builtin_amdgcn_s_sleep(1);
            }
        }
        __syncthreads();
        const int wv = tid >> 6;          // batch 0..3
        const int lane = tid & 63;
        const int base = wv * BLKS_PER_B; // 288 partials per batch = 4x64 + 32
        int s = 0;
#pragma unroll
        for (int k = 0; k < 4; ++k) s += ld_agent_i32(&partial[base + 64 * k + lane]);
        if (lane < 32) s += ld_agent_i32(&partial[base + 256 + lane]);
#pragma unroll
        for (int off = 32; off; off >>= 1) s += __shfl_down(s, off, 64);
        if (lane == 0) {
            float cf = (float)s;
            const float lo = (float)(147456.0 * 0.05);
            const float hi = (float)(147456.0 * 0.95);
            out[NPIX + wv] = (cf >= lo && cf <= hi) ? 1.0f : 0.0f;
        }
    }
}

}  // namespace

extern "C" void kernel_launch(void* const* d_in, const int* in_sizes, int n_in,
                              void* d_out, int out_size, void* d_ws, size_t ws_size,
                              hipStream_t stream) {
    const float* x  = (const float*)d_in[0];
    const float* tg = (const float*)d_in[1];
    const float* fm = (const float*)d_in[2];
    float* out = (float*)d_out;

    char* ws = (char*)d_ws;
    // layout (bytes):
    //   arrive : 0      .. 1024      (16 x 64B)
    //   flags  : 1024   .. 74752     (1152 x 64B)
    //   partial: 74752  .. 79360
    //   pad    : 79360  .. 81920     (overhang-safe; values irrelevant now)
    //   st0    : 81920  .. +NPIX
    //   pad    : 2048
    //   st1    : .. +NPIX
    int* arrive  = (int*)ws;
    int* flags   = (int*)(ws + 1024);
    int* partial = (int*)(ws + 74752);
    unsigned char* st0 = (unsigned char*)(ws + 81920);
    unsigned char* st1 = st0 + NPIX + 2048;

    // zero arrive + flags every call (graph-captured)
    (void)hipMemsetAsync(ws, 0, 74752, stream);

    fused_kernel<<<NBLK, TPB, 0, stream>>>(x, tg, fm, out, arrive, flags,
                                           partial, st0, st1);
}

// Round 15
// 52.391 us; speedup vs baseline: 2.2796x; 1.3437x over previous
//
#include <hip/hip_runtime.h>
#include <math.h>

namespace {

constexpr int Hh = 384;
constexpr int Ww = 384;
constexpr int Bb = 4;
constexpr int HW = Hh * Ww;          // 147456
constexpr int NPIX = Bb * HW;        // 589824
constexpr int ROUNDS = 10;           // 2 mean-field iterations per round
constexpr int TPB = 256;

// 2D tiling: each block owns a 64x8 tile (2 px/thread), 6x48 tiles/batch
constexpr int TILE_W = 64;
constexpr int TILE_H = 8;
constexpr int TX = Ww / TILE_W;              // 6
constexpr int TY = Hh / TILE_H;              // 48
constexpr int BLKS_PER_B = TX * TY;          // 288
constexpr int NBLK = Bb * BLKS_PER_B;        // 1152

// width-2 halo staged per compute round: rows row0-2..row0+9 (12), cols col0-8..col0+71 (80 B)
constexpr int H2DW = 20;                     // 80 B / 4
constexpr int H2TOT = 12 * H2DW;             // 240 dwords

// intermediate s_{2r+1}: extended region rows row0-1..row0+8 (10) x cols col0-1..col0+64 (66)
constexpr int MIDS = 68;                     // byte stride
constexpr int NRING = 148;                   // ring pixels of the 10x66 region

// prologue LDS: fmS[3][12][70] (image rows row0-2.., cols col0-3..) and
// wdir[4][11][68] (lattice rows row0-1.., cols col0-2..; 4 backward taps)
constexpr int FMR = 12, FMC = 70, FMPL = FMR * FMC;       // 840
constexpr int FMTOT = 3 * FMPL;                           // 2520
constexpr int QR = 11, QC = 68, QPL = QR * QC;            // 748
constexpr int QTOT = 4 * QPL;                             // 2992

__device__ __forceinline__ float fsub_rn_(float a, float b) {
    return __fadd_rn(a, -b);
}

__device__ __forceinline__ unsigned ld_agent_u32(const void* p) {
    return __hip_atomic_load((const unsigned*)p, __ATOMIC_RELAXED,
                             __HIP_MEMORY_SCOPE_AGENT);
}
__device__ __forceinline__ void st_agent_u16(void* p, unsigned short v) {
    __hip_atomic_store((unsigned short*)p, v, __ATOMIC_RELAXED,
                       __HIP_MEMORY_SCOPE_AGENT);
}
__device__ __forceinline__ int ld_agent_i32(const int* p) {
    return __hip_atomic_load(p, __ATOMIC_RELAXED, __HIP_MEMORY_SCOPE_AGENT);
}
__device__ __forceinline__ void st_agent_i32(int* p, int v) {
    __hip_atomic_store(p, v, __ATOMIC_RELAXED, __HIP_MEMORY_SCOPE_AGENT);
}

// one mean-field pixel update; base -> top-left tap. FP order identical to ref.
template <int STRIDE>
__device__ __forceinline__ unsigned mf_state(const unsigned char* base,
                                             const float* w9, float tpx,
                                             float Lg45, float Lg55) {
    float a0 = 0.0f, a1 = 0.0f;
#pragma unroll
    for (int ki = 0; ki < 3; ++ki) {
#pragma unroll
        for (int kj = 0; kj < 3; ++kj) {
            const int k = ki * 3 + kj;
            unsigned char s = base[ki * STRIDE + kj];   // garbage when w9[k]==0 -> +0.0
            float u0 = (s & 1) ? Lg55 : Lg45;
            float u1 = (s & 2) ? Lg55 : Lg45;
            a0 = __fadd_rn(a0, __fmul_rn(u0, w9[k]));
            a1 = __fadd_rn(a1, __fmul_rn(u1, w9[k]));
        }
    }
    float f0 = expf(-a0);
    float f1 = __fmul_rn(expf(-a1), tpx);
    f0 = __fadd_rn(f0, 1e-6f);
    f1 = __fadd_rn(f1, 1e-6f);
    float S = __fadd_rn(f0, f1);
    float f0n = __fdiv_rn(f0, S);
    float f1n = __fdiv_rn(f1, S);
    return (f0n > 0.5f ? 1u : 0u) | (f1n > 0.5f ? 2u : 0u);
}

__device__ __forceinline__ void ring_coords(int ri, int& er, int& ec) {
    if (ri < 66)       { er = 0;        ec = ri; }
    else if (ri < 132) { er = 9;        ec = ri - 66; }
    else if (ri < 140) { er = ri - 131; ec = 0; }     // 1..8
    else               { er = ri - 139; ec = 65; }    // 1..8
}

// Flags/skip protocol identical to R14 (proven): word = ((q+2)<<2) |
// (changed_q<<1) | changed_{q-1}; round r waits parts >= r+1; skip iff all 9
// changed_{r-1}==0 (then LDS region is current, nothing staged/stored).
__global__ __launch_bounds__(TPB, 6) void fused_kernel(
        const float* __restrict__ x, const float* __restrict__ t,
        const float* __restrict__ fm, float* __restrict__ out,
        int* __restrict__ arrive, int* __restrict__ flags,
        int* __restrict__ partial,
        unsigned char* __restrict__ st0, unsigned char* __restrict__ st1) {
    const int tid = threadIdx.x;
    const int bid = blockIdx.x;
    const int b = bid / BLKS_PER_B;
    const int rr_ = bid - b * BLKS_PER_B;
    const int ty = rr_ / TX, tx = rr_ - ty * TX;
    const int row0 = ty * TILE_H, col0 = tx * TILE_W;
    const int tr = tid >> 5;              // 0..7
    const int tc = (tid & 31) * 2;        // 0..62
    const int row = row0 + tr, col = col0 + tc;
    const int hw = row * Ww + col;
    const int gp = b * HW + hw;           // gp % 2 == 0

    // lanes 0..7 of wave 0 poll one neighbor each
    bool nactive = false;
    const int* nflag = nullptr;
    if (tid < 8) {
        const int l2 = (tid < 4) ? tid : tid + 1;       // skip center
        const int dy = l2 / 3 - 1, dx = l2 - (l2 / 3) * 3 - 1;
        const int nty = ty + dy, ntx = tx + dx;
        if (nty >= 0 && nty < TY && ntx >= 0 && ntx < TX) {
            nactive = true;
            nflag = &flags[(b * BLKS_PER_B + nty * TX + ntx) << 4];
        }
    }

    const float Lg45 = (float)(-log((double)0.45f));
    const float Lg55 = (float)(-log((double)0.55f));

    // ---- FIRST: s_0 init + flag publish (takes prologue off the chain) ----
    float2 xv = reinterpret_cast<const float2*>(x)[gp >> 1];
    float2 tv = reinterpret_cast<const float2*>(t)[gp >> 1];
    const float tj[2] = {tv.x, tv.y};
    {
        unsigned short pack =
            (unsigned short)(((__fmul_rn(xv.x, tv.x) > 0.5f) ? 2u : 1u) |
                             (((__fmul_rn(xv.y, tv.y) > 0.5f) ? 2u : 1u) << 8));
        st_agent_u16(st0 + gp, pack);
    }
    __syncthreads();                      // drain s_0 stores (vmcnt 0)
    if (tid == 0) st_agent_i32(&flags[bid << 4], (1 << 2) | 3);

    // ---- prologue: shared-memory weight factory ----
    // fmS stage (coalesced, clamped addresses; clamped values never used)
    __shared__ float pbuf[FMTOT + QTOT];  // fmS | wdir
    float* fmS = pbuf;
    float* wdir = pbuf + FMTOT;
    const float* fmb = fm + (size_t)b * 3 * HW;
    for (int i = tid; i < FMTOT; i += TPB) {
        const int c = i / FMPL, rem = i - c * FMPL;
        const int r = rem / FMC, fc = rem - r * FMC;
        const int ir = min(max(row0 - 2 + r, 0), Hh - 1);
        const int ic = min(max(col0 - 3 + fc, 0), Ww - 1);
        fmS[i] = fmb[c * HW + ir * Ww + ic];
    }
    __syncthreads();

    // 4 backward-direction weights per lattice point (mirror-shared, exact):
    // k0=(-1,-1) k1=(-1,0) k2=(-1,+1) k3=(0,-1); center tap == 3.0f exactly.
    const float SPK1 = __fdiv_rn(1.0f, 1800.0f);
    const float SPK2 = __fdiv_rn(2.0f, 1800.0f);
    auto wtap = [&](int fr, int fc, float c0, float c1, float c2, float spk) {
        float d0 = fsub_rn_(__fadd_rn(fmS[0 * FMPL + fr * FMC + fc], 10.0f), c0);
        float d1 = fsub_rn_(__fadd_rn(fmS[1 * FMPL + fr * FMC + fc], 10.0f), c1);
        float d2 = fsub_rn_(__fadd_rn(fmS[2 * FMPL + fr * FMC + fc], 10.0f), c2);
        float ss = __fadd_rn(__fadd_rn(__fmul_rn(d0, d0), __fmul_rn(d1, d1)),
                             __fmul_rn(d2, d2));
        float color = __fmul_rn(-ss, 2.0f);   // == __fdiv_rn(-ss,0.5f) exactly
        return __fmul_rn(3.0f, expf(fsub_rn_(color, spk)));
    };
    for (int i = tid; i < QPL; i += TPB) {
        const int qr = i / QC, qcc = i - qr * QC;
        const int ir = row0 - 1 + qr, ic = col0 - 2 + qcc;
        float w0 = 0.0f, w1 = 0.0f, w2 = 0.0f, w3 = 0.0f;
        if (ir >= 0 && ir < Hh && ic >= 0 && ic < Ww) {
            const int fr = qr + 1, fc = qcc + 1;
            float c0 = __fadd_rn(fmS[0 * FMPL + fr * FMC + fc], 10.0f);
            float c1 = __fadd_rn(fmS[1 * FMPL + fr * FMC + fc], 10.0f);
            float c2 = __fadd_rn(fmS[2 * FMPL + fr * FMC + fc], 10.0f);
            const bool up = (ir - 1 >= 0), lf = (ic - 1 >= 0), rg = (ic + 1 < Ww);
            if (up && lf) w0 = wtap(fr - 1, fc - 1, c0, c1, c2, SPK2);
            if (up)       w1 = wtap(fr - 1, fc,     c0, c1, c2, SPK1);
            if (up && rg) w2 = wtap(fr - 1, fc + 1, c0, c1, c2, SPK2);
            if (lf)       w3 = wtap(fr,     fc - 1, c0, c1, c2, SPK1);
        }
        wdir[0 * QPL + i] = w0;
        wdir[1 * QPL + i] = w1;
        wdir[2 * QPL + i] = w2;
        wdir[3 * QPL + i] = w3;
    }
    __syncthreads();

    // assemble own 2 px weights (lattice qr=tr+1, qcc=tc+j+2)
    float wall[2][9];
#pragma unroll
    for (int j = 0; j < 2; ++j) {
        const int qp = (tr + 1) * QC + (tc + j + 2);
        wall[j][0] = wdir[0 * QPL + qp];
        wall[j][1] = wdir[1 * QPL + qp];
        wall[j][2] = wdir[2 * QPL + qp];
        wall[j][3] = wdir[3 * QPL + qp];
        wall[j][4] = 3.0f;
        wall[j][5] = wdir[3 * QPL + qp + 1];        // E = right's W
        wall[j][6] = wdir[2 * QPL + qp + QC - 1];   // SW = down-left's NE
        wall[j][7] = wdir[1 * QPL + qp + QC];       // S = down's N
        wall[j][8] = wdir[0 * QPL + qp + QC + 1];   // SE = down-right's NW
    }
    // ring weights (lattice qr=er, qcc=ec+1)
    bool ringv = false;
    int rer = 0, rec = 0;
    float rw[9] = {0, 0, 0, 0, 0, 0, 0, 0, 0};
    float rt = 0.0f;
    if (tid < NRING) {
        ring_coords(tid, rer, rec);
        const int irow = row0 - 1 + rer, icol = col0 - 1 + rec;
        ringv = (irow >= 0 && irow < Hh && icol >= 0 && icol < Ww);
        if (ringv) {
            const int qp = rer * QC + (rec + 1);
            rw[0] = wdir[0 * QPL + qp];
            rw[1] = wdir[1 * QPL + qp];
            rw[2] = wdir[2 * QPL + qp];
            rw[3] = wdir[3 * QPL + qp];
            rw[4] = 3.0f;
            rw[5] = wdir[3 * QPL + qp + 1];
            rw[6] = wdir[2 * QPL + qp + QC - 1];
            rw[7] = wdir[1 * QPL + qp + QC];
            rw[8] = wdir[0 * QPL + qp + QC + 1];
            rt = t[(size_t)b * HW + irow * Ww + icol];
        }
    }

    __shared__ unsigned lds_h2[H2TOT];            // staged region (single buffer)
    __shared__ unsigned char lds_mid[10 * MIDS];  // s_{2r+1}, 10x66 used
    __shared__ int sskip;
    __shared__ int schg[4];
    __shared__ int sred[4];

    int pchg = 1;                          // changed_{r-1}, block-uniform

    // ---- 10 rounds x 2 iterations (identical to R14) ----
    for (int r = 0; r < ROUNDS; ++r) {
        const bool fin = (r == ROUNDS - 1);
        const unsigned char* cur = (r & 1) ? st1 : st0;
        unsigned char* nxt = (r & 1) ? st0 : st1;

        // poll: all neighbors part >= r+1; capture their changed_{r-1}
        if (tid < 64) {
            int nchg = 0;
            for (;;) {
                bool ok = true;
                if (nactive) {
                    int f = ld_agent_i32(nflag);
                    int part = f >> 2;
                    ok = (part >= r + 1);
                    if (ok) nchg = (part == r + 1) ? ((f >> 1) & 1) : (f & 1);
                }
                if (__all(ok)) break;
                __builtin_amdgcn_s_sleep(1);
            }
            bool unch = nactive ? (nchg == 0) : true;
            int au = __all(unch);
            if (tid == 0) sskip = au;
        }
        __syncthreads();
        const bool skip = (r > 0) && (sskip != 0) && (pchg == 0);

        const unsigned char* h2b = (const unsigned char*)lds_h2;
        unsigned n2[2];
        int chg;

        if (skip) {
            n2[0] = h2b[(tr + 2) * 80 + tc + 8];
            n2[1] = h2b[(tr + 2) * 80 + tc + 9];
            chg = 0;
            if (!fin && tid == 0)
                st_agent_i32(&flags[bid << 4], ((r + 2) << 2) | (0 << 1) | pchg);
        } else {
            if (tid < H2TOT) {
                const unsigned char* base2 =
                    cur + (size_t)b * HW + (row0 - 2) * Ww + (col0 - 8);
                const int hr = tid / H2DW, hc = tid - hr * H2DW;
                lds_h2[tid] = ld_agent_u32(base2 + hr * Ww + hc * 4);
            }
            __syncthreads();

#pragma unroll
            for (int j = 0; j < 2; ++j) {
                unsigned m = mf_state<80>(h2b + (tr + 1) * 80 + tc + 7 + j,
                                          wall[j], tj[j], Lg45, Lg55);
                lds_mid[(tr + 1) * MIDS + tc + j + 1] = (unsigned char)m;
            }
            if (ringv) {
                unsigned m = mf_state<80>(h2b + rer * 80 + rec + 6,
                                          rw, rt, Lg45, Lg55);
                lds_mid[rer * MIDS + rec] = (unsigned char)m;
            }
            __syncthreads();

#pragma unroll
            for (int j = 0; j < 2; ++j)
                n2[j] = mf_state<MIDS>(lds_mid + tr * MIDS + tc + j,
                                       wall[j], tj[j], Lg45, Lg55);

            bool diff = (n2[0] != (unsigned)h2b[(tr + 2) * 80 + tc + 8]) ||
                        (n2[1] != (unsigned)h2b[(tr + 2) * 80 + tc + 9]);
            {
                int any = __any(diff);
                if ((tid & 63) == 0) schg[tid >> 6] = any;
            }
            if (!fin)
                st_agent_u16(nxt + gp, (unsigned short)(n2[0] | (n2[1] << 8)));
            __syncthreads();              // drains state stores + schg writes
            chg = (schg[0] | schg[1] | schg[2] | schg[3]) ? 1 : 0;
            if (!fin && tid == 0)
                st_agent_i32(&flags[bid << 4], ((r + 2) << 2) | (chg << 1) | pchg);
        }
        pchg = chg;

        if (fin) {
            const float o0 = (n2[0] & 2) ? 1.0f : 0.0f;
            const float o1 = (n2[1] & 2) ? 1.0f : 0.0f;
            reinterpret_cast<float2*>(out)[gp >> 1] = make_float2(o0, o1);
            int cnt = (o0 != 0.0f) + (o1 != 0.0f);
            const int lane = tid & 63;
            const int wv = tid >> 6;
#pragma unroll
            for (int off = 32; off; off >>= 1) cnt += __shfl_down(cnt, off, 64);
            if (lane == 0) sred[wv] = cnt;
            __syncthreads();
            if (tid == 0) {
                int tot = sred[0] + sred[1] + sred[2] + sred[3];
                st_agent_i32(&partial[bid], tot);
            }
        }
    }

    // ---- final global sync (partials), then block 0 reduces -> valid ----
    __syncthreads();                      // drain partial store
    if (tid == 0)
        __hip_atomic_fetch_add(&arrive[(bid & 15) << 4], 1,
                               __ATOMIC_RELAXED, __HIP_MEMORY_SCOPE_AGENT);
    if (bid == 0) {
        if (tid < 64) {
            for (;;) {
                int v = 0;
                if (tid < 16) v = ld_agent_i32(&arrive[tid << 4]);
#pragma unroll
                for (int off = 1; off < 64; off <<= 1) v += __shfl_xor(v, off, 64);
                if (v >= NBLK) break;
                __builtin_amdgcn_s_sleep(1);
            }
        }
        __syncthreads();
        const int wv = tid >> 6;          // batch 0..3
        const int lane = tid & 63;
        const int base = wv * BLKS_PER_B; // 288 partials per batch = 4x64 + 32
        int s = 0;
#pragma unroll
        for (int k = 0; k < 4; ++k) s += ld_agent_i32(&partial[base + 64 * k + lane]);
        if (lane < 32) s += ld_agent_i32(&partial[base + 256 + lane]);
#pragma unroll
        for (int off = 32; off; off >>= 1) s += __shfl_down(s, off, 64);
        if (lane == 0) {
            float cf = (float)s;
            const float lo = (float)(147456.0 * 0.05);
            const float hi = (float)(147456.0 * 0.95);
            out[NPIX + wv] = (cf >= lo && cf <= hi) ? 1.0f : 0.0f;
        }
    }
}

}  // namespace

extern "C" void kernel_launch(void* const* d_in, const int* in_sizes, int n_in,
                              void* d_out, int out_size, void* d_ws, size_t ws_size,
                              hipStream_t stream) {
    const float* x  = (const float*)d_in[0];
    const float* tg = (const float*)d_in[1];
    const float* fm = (const float*)d_in[2];
    float* out = (float*)d_out;

    char* ws = (char*)d_ws;
    // layout (bytes):
    //   arrive : 0      .. 1024      (16 x 64B)
    //   flags  : 1024   .. 74752     (1152 x 64B)
    //   partial: 74752  .. 79360
    //   pad    : 79360  .. 81920     (overhang-safe)
    //   st0    : 81920  .. +NPIX
    //   pad    : 2048
    //   st1    : .. +NPIX
    int* arrive  = (int*)ws;
    int* flags   = (int*)(ws + 1024);
    int* partial = (int*)(ws + 74752);
    unsigned char* st0 = (unsigned char*)(ws + 81920);
    unsigned char* st1 = st0 + NPIX + 2048;

    // zero arrive + flags every call (graph-captured)
    (void)hipMemsetAsync(ws, 0, 74752, stream);

    fused_kernel<<<NBLK, TPB, 0, stream>>>(x, tg, fm, out, arrive, flags,
                                           partial, st0, st1);
}